// Round 14
// baseline (674.946 us; speedup 1.0000x reference)
//
#include <hip/hip_runtime.h>
#include <cstdint>
#include <cstddef>

#define Bn 128
#define Ln 1024
#define Fn 128
#define Hn 64
#define NGn 256           // 4*H
#define NCn 16
#define IN_DIM (Hn + Fn*Hn)   // 8256

typedef float    f32x4 __attribute__((ext_vector_type(4)));
typedef float    f32x2 __attribute__((ext_vector_type(2)));
typedef _Float16 f16x8 __attribute__((ext_vector_type(8)));
typedef _Float16 f16x2 __attribute__((ext_vector_type(2)));

union U8 { f16x8 v; f16x2 p[4]; };

// ---- dynamic LDS carve (bytes) ----
#define OFF_A    0                 // 131072  A[m][256] f32 preactivation cache
#define OFF_H    131072            // 16384   h16[m][64] f16 state
#define OFF_PK   147456            // 8192    pk[j] = {x, dec} f32x2
#define OFF_MF   155648            // 1024    mf[j] = m | (hazard<<7)
#define OFF_C    156672            // 256
#define OFF_RED  156928            // 256
#define OFF_LOG  157184            // 64
#define LDS_TOTAL 157248           // < 160 KiB

__device__ __forceinline__ float fsigm(float x) {
    return __fdividef(1.0f, 1.0f + __expf(-x));
}
__device__ __forceinline__ float ftanh(float x) {
    float e = __expf(2.0f * x);
    return 1.0f - __fdividef(2.0f, e + 1.0f);
}
__device__ __forceinline__ float sigm_slow(float x) { return 1.0f / (1.0f + expf(-x)); }

#if __has_builtin(__builtin_amdgcn_fdot2)
#define DOT2(WP, HP, ACC) __builtin_amdgcn_fdot2((WP), (HP), (ACC), false)
#else
#define DOT2(WP, HP, ACC) fmaf((float)(WP)[0], (float)(HP)[0], \
                               fmaf((float)(WP)[1], (float)(HP)[1], (ACC)))
#endif

// Gw[(m*8 + c)*256 + r] (f16x8) = W_gates[m][r][1+8c .. 8+8c]  (r = gate row, natural order)
// Gwb[m*256 + r] (f32x2)        = { W_gates[m][r][0], b_gates[m][r] }
__global__ __launch_bounds__(256)
void prep_f16(const float* __restrict__ Wg, const float* __restrict__ bg,
              f16x8* __restrict__ Gw, f32x2* __restrict__ Gwb)
{
    const int m = blockIdx.x, r = threadIdx.x;
    const float* src = Wg + ((size_t)m * NGn + r) * 65;
    f32x2 wb; wb[0] = src[0]; wb[1] = bg[m * NGn + r];
    Gwb[((size_t)m << 8) + r] = wb;
#pragma unroll
    for (int c = 0; c < 8; ++c) {
        f16x8 v;
#pragma unroll
        for (int e = 0; e < 8; ++e) v[e] = (_Float16)src[1 + 8 * c + e];
        Gw[((size_t)m << 11) + (c << 8) + r] = v;
    }
}

// issue W[M] (8 x f16x8, fully coalesced 4KB/instr) into register slab WN
#define ISSUEW(WN, M)                                                           \
    do {                                                                        \
        const f16x8* wp_ = Gw + (((size_t)(M)) << 11) + tid;                    \
        _Pragma("unroll")                                                       \
        for (int c_ = 0; c_ < 8; ++c_) WN[c_] = wp_[c_ << 8];                   \
    } while (0)

// issue wx/bias for scan (4 f32x2 per lane) into WBN
#define ISSUEWB(WBN, M)                                                         \
    do {                                                                        \
        const f32x2* bp_ = Gwb + (((size_t)(M)) << 8);                          \
        _Pragma("unroll")                                                       \
        for (int g_ = 0; g_ < 4; ++g_) WBN[g_] = bp_[(g_ << 6) + l];            \
    } while (0)

// refresh A[MP] = W[MP] @ h16[MP]  (thread tid owns gate row tid: 32 dot2)
#define REFRESH(WC, MP)                                                         \
    do {                                                                        \
        const f16x8* hp_ = (const f16x8*)(h16 + ((MP) << 6));                   \
        U8 hr_[8];                                                              \
        _Pragma("unroll")                                                       \
        for (int c_ = 0; c_ < 8; ++c_) hr_[c_].v = hp_[c_];   /* broadcast */   \
        float ar_ = 0.0f;                                                       \
        _Pragma("unroll")                                                       \
        for (int c_ = 0; c_ < 8; ++c_) {                                        \
            U8 wc_; wc_.v = WC[c_];                                             \
            _Pragma("unroll")                                                   \
            for (int e_ = 0; e_ < 4; ++e_)                                      \
                ar_ = DOT2(wc_.p[e_], hr_[c_].p[e_], ar_);                      \
        }                                                                       \
        A_s[((MP) << 8) + tid] = ar_;                                           \
    } while (0)

// One step: scan from cached A[m_cur]; refresh(j-1) off the critical chain.
#define STEPA(WC, WN, WBC, WBN)                                                 \
    {                                                                           \
        const bool hz_ = (hzc != 0) && (j >= 1);                                \
        ISSUEW(WN, m_cur);                                                      \
        if (hz_) {   /* m_cur == m_prev: A[m_cur] refresh must land first */    \
            REFRESH(WC, m_prev);                                                \
            asm volatile("s_waitcnt lgkmcnt(0)" ::: "memory");                  \
            __builtin_amdgcn_s_barrier();                                       \
        }                                                                       \
        const float a0_ = A_s[(m_cur << 8) + l];                                \
        const float a1_ = A_s[(m_cur << 8) + 64 + l];                           \
        const float a2_ = A_s[(m_cur << 8) + 128 + l];                          \
        const float a3_ = A_s[(m_cur << 8) + 192 + l];                          \
        const int jn_ = (j + 1 < len) ? j + 1 : j;                              \
        const unsigned char mfn_ = mf_s[jn_];                                   \
        const f32x2 pkn_ = pk_s[jn_];                                           \
        const int m_nx_ = mfn_ & 0x7f;                                          \
        ISSUEWB(WBN, m_nx_);                                                    \
        const float gi_ = fmaf(dec, a0_, fmaf(xv, WBC[0][0], WBC[0][1]));       \
        const float gf_ = fmaf(dec, a1_, fmaf(xv, WBC[1][0], WBC[1][1]));       \
        const float go_ = fmaf(dec, a2_, fmaf(xv, WBC[2][0], WBC[2][1]));       \
        const float gc_ = fmaf(dec, a3_, fmaf(xv, WBC[3][0], WBC[3][1]));       \
        const float cn_ = fmaf(fsigm(gf_), cu, fsigm(gi_) * ftanh(gc_));        \
        cu = cn_;                                                               \
        const float hv_ = fsigm(go_) * ftanh(cn_);                              \
        if (w == 0) h16[(m_cur << 6) + l] = (_Float16)hv_;                      \
        if (!hz_ && j >= 1) REFRESH(WC, m_prev);                                \
        asm volatile("s_waitcnt lgkmcnt(0)" ::: "memory");                      \
        __builtin_amdgcn_s_barrier();                                           \
        m_prev = m_cur; m_cur = m_nx_; hzc = (int)(mfn_ >> 7);                  \
        xv = pkn_[0]; dec = pkn_[1];                                            \
    }

__global__ __launch_bounds__(256, 1)
void lstm_pre(const float* __restrict__ X, const int* __restrict__ lengths,
              const f16x8* __restrict__ Gw, const f32x2* __restrict__ Gwb,
              const float* __restrict__ wdec, const float* __restrict__ bdec,
              const float* __restrict__ Wo, const float* __restrict__ bo,
              float* __restrict__ out)
{
    extern __shared__ char smem[];
    float*    A_s  = (float*)(smem + OFF_A);
    _Float16* h16  = (_Float16*)(smem + OFF_H);
    f32x2*    pk_s = (f32x2*)(smem + OFF_PK);
    unsigned char* mf_s = (unsigned char*)(smem + OFF_MF);
    float* c_s = (float*)(smem + OFF_C);
    float* red_lds   = (float*)(smem + OFF_RED);
    float* logit_lds = (float*)(smem + OFF_LOG);

    const int b   = blockIdx.x;
    const int tid = threadIdx.x;
    const int l   = tid & 63;          // lane == hidden unit u
    const int w   = tid >> 6;          // wave index

    const float* mrow = X + ((size_t)b * 4 + 1) * Ln;
    const float* xrow = X + ((size_t)b * 4 + 2) * Ln;
    const float* drow = X + ((size_t)b * 4 + 3) * Ln;

    // stage wdec/bdec temporarily in the (not-yet-used) A region
    if (tid < Fn) { A_s[tid] = wdec[tid]; A_s[Fn + tid] = bdec[tid]; }
    __syncthreads();
    for (int jj = tid; jj < Ln; jj += 256) {
        const int   m   = (int)mrow[jj];
        const float dec = __expf(-fmaxf(0.0f, fmaf(A_s[m], drow[jj], A_s[Fn + m])));
        f32x2 t; t[0] = xrow[jj]; t[1] = dec;
        pk_s[jj] = t;
        int hz = 0;
        if (jj > 0) hz = (m == (int)mrow[jj - 1]) ? 0x80 : 0;
        mf_s[jj] = (unsigned char)(m | hz);
    }
    __syncthreads();
    // zero A (h = 0 -> all preactivations 0) and h16
    for (int i = tid; i < Fn * NGn; i += 256) A_s[i] = 0.0f;
    {
        f16x8 hzv;
#pragma unroll
        for (int e = 0; e < 8; ++e) hzv[e] = (_Float16)0.0f;
        for (int i = tid; i < (Fn * Hn / 8); i += 256) ((f16x8*)h16)[i] = hzv;
    }
    __syncthreads();

    int len = lengths[b];
    if (len > Ln) len = Ln;

    float cu = 0.0f;   // c[l], replicated across the 4 waves

    if (len > 0) {
        const unsigned char mf0 = mf_s[0];
        int   m_cur = mf0 & 0x7f;
        int   hzc   = 0;           // step 0 never hazards
        int   m_prev = 0;
        f32x2 p0 = pk_s[0];
        float xv = p0[0], dec = p0[1];

        f16x8 wA[8], wB[8];
        f32x2 bA[4], bB[4];
        ISSUEWB(bA, m_cur);

        int j = 0;
        for (;;) {
            STEPA(wA, wB, bA, bB); if (++j >= len) break;
            STEPA(wB, wA, bB, bA); if (++j >= len) break;
        }
    }
    if (w == 0) c_s[l] = cu;
    __syncthreads();

    // ---- output head: logits = W_out @ [c; h.flatten()] + b_out, softmax ----
    float p[NCn];
#pragma unroll
    for (int c = 0; c < NCn; ++c) p[c] = 0.0f;
    for (int i = tid; i < IN_DIM; i += 256) {
        const float fv = (i < Hn) ? c_s[i] : (float)h16[i - Hn];
#pragma unroll
        for (int c = 0; c < NCn; ++c)
            p[c] = fmaf(Wo[(size_t)c * IN_DIM + i], fv, p[c]);
    }
#pragma unroll
    for (int c = 0; c < NCn; ++c) {
        float v = p[c];
#pragma unroll
        for (int off = 32; off > 0; off >>= 1) v += __shfl_down(v, off, 64);
        if (l == 0) red_lds[w * NCn + c] = v;
    }
    __syncthreads();
    if (tid < NCn) {
        logit_lds[tid] = red_lds[tid] + red_lds[NCn + tid] +
                         red_lds[2 * NCn + tid] + red_lds[3 * NCn + tid] + bo[tid];
    }
    __syncthreads();
    if (tid == 0) {
        float mx = logit_lds[0];
        for (int c = 1; c < NCn; ++c) mx = fmaxf(mx, logit_lds[c]);
        float e[NCn], sm = 0.0f;
        for (int c = 0; c < NCn; ++c) { e[c] = expf(logit_lds[c] - mx); sm += e[c]; }
        const float inv = 1.0f / sm;
        for (int c = 0; c < NCn; ++c) out[(size_t)b * NCn + c] = e[c] * inv;
    }
}

// ---- fallback (no workspace): raw f32 weights each step ----
__global__ __launch_bounds__(256)
void lstm_fallback(const float* __restrict__ X, const int* __restrict__ lengths,
                   const float* __restrict__ Wg, const float* __restrict__ bg,
                   const float* __restrict__ wdec, const float* __restrict__ bdec,
                   const float* __restrict__ Wo, const float* __restrict__ bo,
                   float* __restrict__ out)
{
    __shared__ __align__(16) float h_lds[Fn * Hn];
    __shared__ float c_lds[Hn];
    __shared__ int   m_lds[Ln];
    __shared__ float x_lds[Ln];
    __shared__ float d_lds[Ln];
    __shared__ float wd_lds[Fn], bd_lds[Fn];
    __shared__ float red_lds[4 * NCn];
    __shared__ float logit_lds[NCn];

    const int b   = blockIdx.x;
    const int tid = threadIdx.x;
    const int l   = tid & 63;
    const int w   = tid >> 6;
    const int q   = l & 3;
    const int u   = w * 16 + (l >> 2);

    const float* mrow = X + ((size_t)b * 4 + 1) * Ln;
    const float* xrow = X + ((size_t)b * 4 + 2) * Ln;
    const float* drow = X + ((size_t)b * 4 + 3) * Ln;

    for (int i = tid; i < Fn * Hn; i += 256) h_lds[i] = 0.0f;
    if (tid < Hn) c_lds[tid] = 0.0f;
    if (tid < Fn) { wd_lds[tid] = wdec[tid]; bd_lds[tid] = bdec[tid]; }
    for (int i = tid; i < Ln; i += 256) {
        m_lds[i] = (int)mrow[i];
        x_lds[i] = xrow[i];
        d_lds[i] = drow[i];
    }
    __syncthreads();

    int len = lengths[b];
    if (len > Ln) len = Ln;
    const int g_raw = q * 64 + u;

    for (int j = 0; j < len; ++j) {
        const int   mj = m_lds[j];
        const float xj = x_lds[j];
        const float dj = d_lds[j];
        const float dec = expf(-fmaxf(0.0f, fmaf(wd_lds[mj], dj, bd_lds[mj])));
        const float4* hp = (const float4*)(h_lds + mj * Hn);
        const float* row = Wg + ((size_t)mj * NGn + g_raw) * 65;
        float acc = fmaf(row[0], xj, bg[mj * NGn + g_raw]);
        float a0 = 0.f, a1 = 0.f, a2 = 0.f, a3 = 0.f;
#pragma unroll
        for (int k4 = 0; k4 < 16; ++k4) {
            float4 hv = hp[k4];
            a0 = fmaf(row[1 + 4*k4 + 0], hv.x, a0);
            a1 = fmaf(row[1 + 4*k4 + 1], hv.y, a1);
            a2 = fmaf(row[1 + 4*k4 + 2], hv.z, a2);
            a3 = fmaf(row[1 + 4*k4 + 3], hv.w, a3);
        }
        acc = fmaf(dec, (a0 + a1) + (a2 + a3), acc);
        const int base = l & ~3;
        const float gi = __shfl(acc, base + 0, 64);
        const float gf = __shfl(acc, base + 1, 64);
        const float go = __shfl(acc, base + 2, 64);
        const float gc = __shfl(acc, base + 3, 64);
        __syncthreads();
        const float c_new = fmaf(sigm_slow(gf), c_lds[u], sigm_slow(gi) * tanhf(gc));
        if (q == 0) {
            c_lds[u] = c_new;
            h_lds[mj * Hn + u] = sigm_slow(go) * tanhf(c_new);
        }
        __syncthreads();
    }

    float p[NCn];
#pragma unroll
    for (int c = 0; c < NCn; ++c) p[c] = 0.0f;
    for (int i = tid; i < IN_DIM; i += 256) {
        const float fv = (i < Hn) ? c_lds[i] : h_lds[i - Hn];
#pragma unroll
        for (int c = 0; c < NCn; ++c)
            p[c] = fmaf(Wo[(size_t)c * IN_DIM + i], fv, p[c]);
    }
#pragma unroll
    for (int c = 0; c < NCn; ++c) {
        float v = p[c];
#pragma unroll
        for (int off = 32; off > 0; off >>= 1) v += __shfl_down(v, off, 64);
        if (l == 0) red_lds[w * NCn + c] = v;
    }
    __syncthreads();
    if (tid < NCn) {
        logit_lds[tid] = red_lds[tid] + red_lds[NCn + tid] +
                         red_lds[2 * NCn + tid] + red_lds[3 * NCn + tid] + bo[tid];
    }
    __syncthreads();
    if (tid == 0) {
        float mx = logit_lds[0];
        for (int c = 1; c < NCn; ++c) mx = fmaxf(mx, logit_lds[c]);
        float e[NCn], s = 0.0f;
        for (int c = 0; c < NCn; ++c) { e[c] = expf(logit_lds[c] - mx); s += e[c]; }
        const float inv = 1.0f / s;
        for (int c = 0; c < NCn; ++c) out[(size_t)b * NCn + c] = e[c] * inv;
    }
}

extern "C" void kernel_launch(void* const* d_in, const int* in_sizes, int n_in,
                              void* d_out, int out_size, void* d_ws, size_t ws_size,
                              hipStream_t stream)
{
    const float* X      = (const float*)d_in[0];
    const int*   len    = (const int*)  d_in[1];
    const float* Wg     = (const float*)d_in[2];
    const float* bg     = (const float*)d_in[3];
    const float* wdec   = (const float*)d_in[4];
    const float* bdec   = (const float*)d_in[5];
    const float* Wo     = (const float*)d_in[6];
    const float* bo     = (const float*)d_in[7];
    float*       out    = (float*)d_out;

    const size_t gw_bytes  = (size_t)Fn * 2048 * sizeof(f16x8);   // 4,194,304
    const size_t gwb_bytes = (size_t)Fn * 256 * sizeof(f32x2);    // 262,144
    const size_t need      = gw_bytes + gwb_bytes;

    if (ws_size >= need) {
        f16x8* Gw  = (f16x8*)d_ws;
        f32x2* Gwb = (f32x2*)((char*)d_ws + gw_bytes);
        prep_f16<<<Fn, 256, 0, stream>>>(Wg, bg, Gw, Gwb);
        (void)hipFuncSetAttribute((const void*)lstm_pre,
                                  hipFuncAttributeMaxDynamicSharedMemorySize,
                                  LDS_TOTAL);
        lstm_pre<<<Bn, 256, LDS_TOTAL, stream>>>(X, len, Gw, Gwb,
                                                 wdec, bdec, Wo, bo, out);
    } else {
        lstm_fallback<<<Bn, 256, 0, stream>>>(X, len, Wg, bg,
                                              wdec, bdec, Wo, bo, out);
    }
}